// Round 4
// baseline (354.248 us; speedup 1.0000x reference)
//
#include <hip/hip_runtime.h>

// Problem: out[j] = max(x[j], -c[rank_j]) per row, rank_j = position of j in
// stable ascending sort of key = x*rho.  B=4096 rows, P=8192.
//
// R4: de-serialize the rank loop. R3's phase 7 was a serial dependent-LDS
// while-loop (read -> waitcnt -> cmp per iteration, wave runs max-over-lanes
// trip count) -- the ~49% idle gap at 51% VALUBusy. Replace with a fixed
// 8-slot predicated window: 8 independent ds_reads through a common base
// (merge to ds_read2_b32, one latency), 8 branchless compare-adds, plus a
// rare exact fallback for bins > 8 (P ~ 1e-6 per element). mem gets +8 pad
// words so the window never leaves allocated LDS; out-of-bin lanes are
// predicated off ((lo+i) < hi), so garbage reads are never counted.

constexpr int P_LEN  = 8192;            // row length == #bins (13 bits)
constexpr int BDIM   = 1024;            // threads per block
constexpr int EPT    = P_LEN / BDIM;    // 8 elements per thread
constexpr int NW     = BDIM / 64;       // 16 waves
constexpr int CWORDS = P_LEN / 2;       // 4096 packed counter words
constexpr int WIN    = 8;               // rank fast-path window

__device__ __forceinline__ unsigned fkey(float f) {
    unsigned u = __float_as_uint(f);
    // order-preserving map: negatives -> ~u, positives -> u|sign
    return (u & 0x80000000u) ? ~u : (u | 0x80000000u);
}

// packed-counter helpers: bin v in [0,8192) lives in half (v>>12) of word (v&4095)
__device__ __forceinline__ unsigned pk_word(unsigned v) { return v & (CWORDS - 1u); }
__device__ __forceinline__ unsigned pk_inc(unsigned v)  { return (v & (unsigned)CWORDS) ? 0x10000u : 1u; }
__device__ __forceinline__ unsigned pk_get(unsigned w, unsigned v) { return (w >> ((v >> 12) << 4)) & 0xFFFFu; }
// ushort index of bin v's half (little-endian: lo half = 2*word, hi = 2*word+1)
__device__ __forceinline__ unsigned pk_us(unsigned v)   { return ((v & (CWORDS - 1u)) << 1) | (v >> 12); }

// In-place exclusive scan of 8192 packed counts (bin order: all lo halves 0..4095,
// then all hi halves). After: word w = (startLo(w)) | (startHi(w) << 16).
// wt: NW+1 scratch words. Fully wave-parallel (no serial thread-0 loop).
__device__ __forceinline__ void scan_packed(unsigned* cnt, unsigned* wt,
                                            int t, int lane, int wid)
{
    uint4 cw = ((const uint4*)cnt)[t];               // words 4t..4t+3
    const unsigned p1 = cw.x, p2 = cw.x + cw.y, p3 = cw.x + cw.y + cw.z;
    const unsigned s  = p3 + cw.w;                   // packed per-thread sums
    unsigned incl = s;
#pragma unroll
    for (int d = 1; d < 64; d <<= 1) {
        unsigned v = __shfl_up(incl, d, 64);
        if (lane >= d) incl += v;
    }
    if (lane == 63) wt[wid] = incl;                  // packed wave totals
    __syncthreads();
    if (t < 64) {                                    // wave 0 scans the 16 totals
        unsigned v = (lane < NW) ? wt[lane] : 0u;
        const unsigned orig = v;
#pragma unroll
        for (int d = 1; d < NW; d <<= 1) {
            unsigned u = __shfl_up(v, d, 64);
            if (lane >= d) v += u;
        }
        if (lane < NW)     wt[lane] = v - orig;      // exclusive wave prefix
        if (lane == NW - 1) wt[NW]  = v;             // packed grand totals
    }
    __syncthreads();
    const unsigned base = wt[wid] + (incl - s);      // packed exclusive prefix
    const unsigned totL = wt[NW] & 0xFFFFu;          // #elements in lo-half bins
    const unsigned q0 = base, q1 = base + p1, q2 = base + p2, q3 = base + p3;
    uint4 out;
    out.x = (q0 & 0xFFFFu) | ((totL + (q0 >> 16)) << 16);
    out.y = (q1 & 0xFFFFu) | ((totL + (q1 >> 16)) << 16);
    out.z = (q2 & 0xFFFFu) | ((totL + (q2 >> 16)) << 16);
    out.w = (q3 & 0xFFFFu) | ((totL + (q3 >> 16)) << 16);
    ((uint4*)cnt)[t] = out;
    __syncthreads();
}

__global__ __launch_bounds__(BDIM, 8)   // 8 waves/SIMD -> 2 blocks/CU; VGPR <= 64
void qp_rank_kernel(const float* __restrict__ x,
                    const float* __restrict__ rho,
                    const float* __restrict__ c,
                    float* __restrict__ out)
{
    __shared__ unsigned cnt[CWORDS];        // 16 KB packed counters/starts/ends
    __shared__ unsigned mem[P_LEN + WIN];   // 32 KB members + window pad
    __shared__ unsigned wt[NW + 1];         // scan scratch

    const int row  = blockIdx.x;
    const int t    = threadIdx.x;
    const int j0   = t * EPT;
    const int lane = t & 63;
    const int wid  = t >> 6;

    const float* __restrict__ xr   = x   + (size_t)row * P_LEN;
    const float* __restrict__ rr   = rho + (size_t)row * P_LEN;
    float*       __restrict__ outr = out + (size_t)row * P_LEN;
    const unsigned short* usview = (const unsigned short*)cnt;

    // ---- phase 0: zero packed histogram (1 uint4 per thread) ----
    const uint4 z4 = make_uint4(0u, 0u, 0u, 0u);
    ((uint4*)cnt)[t] = z4;
    __syncthreads();

    // ---- phase 1: load, keys, level-1 histogram (top 13 bits) ----
    float4 xa = ((const float4*)(xr + j0))[0];
    float4 xb = ((const float4*)(xr + j0))[1];
    float4 ra = ((const float4*)(rr + j0))[0];
    float4 rb = ((const float4*)(rr + j0))[1];
    float xs[EPT] = {xa.x, xa.y, xa.z, xa.w, xb.x, xb.y, xb.z, xb.w};
    float rs[EPT] = {ra.x, ra.y, ra.z, ra.w, rb.x, rb.y, rb.z, rb.w};
    unsigned key[EPT];
#pragma unroll
    for (int k = 0; k < EPT; ++k) {
        key[k] = fkey(xs[k] * rs[k]);
        const unsigned b = key[k] >> 19;
        atomicAdd(&cnt[pk_word(b)], pk_inc(b));
    }
    __syncthreads();

    // ---- phase 2: scan1 -> packed starts of level-1 bins ----
    scan_packed(cnt, wt, t, lane, wid);

    // ---- phase 3: adaptive refinement: bin2 = s_b + (sz_b * r) >> 13 ----
    // r = next 13 key bits. Monotone re-binning onto position space [0,8192),
    // disjoint ordered ranges per b -> same bin2 implies same top-13 key bits.
    unsigned bin2[EPT];
#pragma unroll
    for (int k = 0; k < EPT; ++k) {
        const unsigned b   = key[k] >> 19;
        const unsigned s_b = usview[pk_us(b)];
        const unsigned e_b = (b == (unsigned)(P_LEN - 1)) ? (unsigned)P_LEN
                                                          : usview[pk_us(b + 1)];
        const unsigned sz  = e_b - s_b;
        const unsigned r   = (key[k] >> 6) & 0x1FFFu;
        bin2[k] = s_b + ((sz * r) >> 13);
    }
    __syncthreads();   // all starts1 reads complete before re-zero

    // ---- phase 4: re-zero, level-2 histogram (near-conflict-free) ----
    ((uint4*)cnt)[t] = z4;
    __syncthreads();
#pragma unroll
    for (int k = 0; k < EPT; ++k)
        atomicAdd(&cnt[pk_word(bin2[k])], pk_inc(bin2[k]));
    __syncthreads();

    // ---- phase 5: scan2 -> packed starts of level-2 bins ----
    scan_packed(cnt, wt, t, lane, wid);

    // ---- phase 6: scatter residuals; cnt halves become bin2 ends ----
    unsigned mine[EPT];
#pragma unroll
    for (int k = 0; k < EPT; ++k) {
        mine[k] = (key[k] << 13) | (unsigned)(j0 + k);
        const unsigned b2 = bin2[k];
        const unsigned old = atomicAdd(&cnt[pk_word(b2)], pk_inc(b2));
        mem[pk_get(old, b2)] = mine[k];
    }
    __syncthreads();

    // ---- phase 7: exact rank, batched 8-slot window (branchless fast path) ----
    unsigned rnk[EPT];
#pragma unroll
    for (int k = 0; k < EPT; ++k) {
        const unsigned b2 = bin2[k];
        const unsigned lo = (b2 == 0u) ? 0u : usview[pk_us(b2 - 1)];
        const unsigned hi = usview[pk_us(b2)];
        const unsigned m  = mine[k];
        const unsigned* mp = mem + lo;     // common base -> ds_read2_b32 merging
        unsigned w[WIN];
#pragma unroll
        for (int i = 0; i < WIN; ++i) w[i] = mp[i];   // all reads in flight at once
        unsigned r = lo;
#pragma unroll
        for (int i = 0; i < WIN; ++i)
            r += ((lo + (unsigned)i < hi) && (w[i] < m)) ? 1u : 0u;
        // rare exact fallback: bin2 larger than WIN (Poisson(1) tail)
        unsigned q = lo + WIN;
#pragma unroll 1
        while (q < hi) { r += (mem[q] < m) ? 1u : 0u; ++q; }
        rnk[k] = r;
    }

    // ---- phase 8: batched c gathers (8 loads in flight), fused epilogue ----
    float res[EPT];
#pragma unroll
    for (int k = 0; k < EPT; ++k) res[k] = fmaxf(xs[k], -c[rnk[k]]);
    ((float4*)(outr + j0))[0] = make_float4(res[0], res[1], res[2], res[3]);
    ((float4*)(outr + j0))[1] = make_float4(res[4], res[5], res[6], res[7]);
}

extern "C" void kernel_launch(void* const* d_in, const int* in_sizes, int n_in,
                              void* d_out, int out_size, void* d_ws, size_t ws_size,
                              hipStream_t stream) {
    const float* x   = (const float*)d_in[0];
    const float* rho = (const float*)d_in[1];
    const float* c   = (const float*)d_in[2];
    float* out = (float*)d_out;
    const int rows = in_sizes[0] / P_LEN;   // 4096
    qp_rank_kernel<<<rows, BDIM, 0, stream>>>(x, rho, c, out);
}